// Round 20
// baseline (526.932 us; speedup 1.0000x reference)
//
#include <hip/hip_runtime.h>
#include <math.h>

typedef unsigned short u16;
typedef unsigned int   u32;
typedef __attribute__((ext_vector_type(8))) short short8;
typedef __attribute__((ext_vector_type(4))) float f32x4;

typedef const void __attribute__((address_space(1))) gvoid_t;
typedef void       __attribute__((address_space(3))) svoid_t;

__device__ __forceinline__ void gload_lds16(const void* g, void* l){
    __builtin_amdgcn_global_load_lds((gvoid_t*)g, (svoid_t*)l, 16, 0, 0);
}

__device__ __forceinline__ float gelu_f(float x){
    return 0.5f * x * (1.0f + erff(x * 0.70710678118654752f));
}
__device__ __forceinline__ u16 f2b(float x){
    union{float f; u32 u;} v; v.f = x;
    u32 r = (v.u + 0x7fffu + ((v.u >> 16) & 1u)) >> 16;
    return (u16)r;
}
__device__ __forceinline__ float b2f(u16 h){
    union{u32 u; float f;} v; v.u = ((u32)h) << 16; return v.f;
}

// ===================== bf16 MFMA GEMM =====================
// Tile 128x128, BK=64, 4 waves, XOR-swizzled LDS, global_load_lds staging,
// T1 XCD-chunked block swizzle. MINW = min waves/EU occupancy hint.
// EPI: 0:+bias->bf16  1:+bias,GELU->bf16  3:/(rowv[r]+1e-8)->bf16
//      8:plain bf16 store (per-splitK slice bz*sC; splitK=1 -> per-batch)
//      9:+bias+resid(bf16,ldr)->f32 DIRECT scatter
//      10:FAVOR dual (in-GEMM xd): z0 transposed kpT store; z1 qp row store->resid
//      11:+bias+resid(bf16,ldr)->bf16
//      12:+bias->bf16 row store; col-tiles >=768 ALSO transposed into resid[ldr] (vT)
//      13:in-GEMM Dn: kps[]=rowv (192 f32, LDS); dnacc += A-frag * kps during
//         COMPUTE (logical k = t*64+(kk*4+g)*8+e, same derivation as EPI10);
//         epilogue divides by (Dn+1e-8) -> bf16. Removes the dn_kernel pass.
template<int EPI, int GUARD, int CGUARD, int MINW>
__global__ __launch_bounds__(256, MINW)
void gemm_bf16(const u16* __restrict__ A, int lda,
               const u16* __restrict__ B, int ldb,
               void* __restrict__ Cv, int ldc,
               const float* __restrict__ bias,
               const float* __restrict__ rowv,
               void* __restrict__ resid, int ldr,
               int Mrows, int Ncols, int K, int splitK,
               long sA, long sB, long sC, long sRV,
               float scale)
{
    const int bz = blockIdx.z;
    const int b  = bz / splitK, kc = bz % splitK;
    A += (long)b * sA;  B += (long)b * sB;
    const float* rv = (EPI == 3 || EPI == 13) ? rowv + (long)b * sRV : nullptr;

    __shared__ u16 SMEM[16384];     // 32KB
    __shared__ float xds[128];
    __shared__ float kps[192];      // EPI13: kpsum for this batch
    u16* const As = SMEM;
    u16* const Bs = SMEM + 8192;

    const int tid = threadIdx.x;

    const int gx  = gridDim.x;
    const int nwg = gx * gridDim.y;
    const int L   = blockIdx.y * gx + blockIdx.x;
    const int q8  = nwg >> 3, r8 = nwg & 7;
    const int xc  = L & 7,   i8 = L >> 3;
    const int nid = (xc < r8 ? xc * (q8 + 1) : r8 * (q8 + 1) + (xc - r8) * q8) + i8;
    const int row0 = (nid / gx) * 128, col0 = (nid % gx) * 128;

    f32x4 acc[4][4] = {};
    float sqacc[4] = {0.f, 0.f, 0.f, 0.f};   // EPI10: sum a^2 ; EPI13: sum a*kps

    const int l  = tid & 63, w4 = tid >> 6;
    const int wr = w4 >> 1, wc = w4 & 1;
    const int g  = l >> 4,  mr = l & 15;

    const int kLen   = K / splitK;
    const int kStart = kc * kLen;
    const int nt     = kLen / 64;

    const int m0   = w4 * 8 + (l >> 3);
    const int k8s  = (l & 7) ^ (m0 & 7);
    const int lBase = w4 * 512 + l * 8;
    const u16* gA0 = A + (long)(row0 + m0) * lda + kStart + k8s * 8;
    const u16* gB0 = B + (long)(col0 + m0) * ldb + kStart + k8s * 8;

    if (EPI == 13 && tid < 192) kps[tid] = rv[tid];

    int aOff[4], bOff[4], sl[2];
    #pragma unroll
    for (int i = 0; i < 4; i++){
        aOff[i] = (wr * 64 + i * 16 + mr) * 64;
        bOff[i] = (wc * 64 + i * 16 + mr) * 64;
    }
    #pragma unroll
    for (int kk = 0; kk < 2; kk++)
        sl[kk] = (((kk * 4 + g) ^ (mr & 7)) & 7) * 8;

    for (int t = 0; t < nt; t++){
        __syncthreads();
        #pragma unroll
        for (int q = 0; q < 4; q++){
            gload_lds16(gA0 + (long)q * 32 * lda + t * 64, &As[lBase + q * 2048]);
            gload_lds16(gB0 + (long)q * 32 * ldb + t * 64, &Bs[lBase + q * 2048]);
        }
        __syncthreads();

        short8 af[2][4], bfr[2][4];
        #pragma unroll
        for (int kk = 0; kk < 2; kk++)
            #pragma unroll
            for (int i = 0; i < 4; i++){
                af[kk][i]  = *(const short8*)&As[aOff[i] + sl[kk]];
                bfr[kk][i] = *(const short8*)&Bs[bOff[i] + sl[kk]];
            }
        if (EPI == 10){
            #pragma unroll
            for (int kk = 0; kk < 2; kk++)
                #pragma unroll
                for (int i = 0; i < 4; i++)
                    #pragma unroll
                    for (int e = 0; e < 8; e++){
                        float f_ = b2f((u16)af[kk][i][e]);
                        sqacc[i] += f_ * f_;
                    }
        }
        if (EPI == 13){
            #pragma unroll
            for (int kk = 0; kk < 2; kk++){
                const int kb = t * 64 + (kk * 4 + g) * 8;
                #pragma unroll
                for (int e = 0; e < 8; e++){
                    const float kv = kps[kb + e];
                    #pragma unroll
                    for (int i = 0; i < 4; i++)
                        sqacc[i] += b2f((u16)af[kk][i][e]) * kv;
                }
            }
        }
        #pragma unroll
        for (int kk = 0; kk < 2; kk++)
            #pragma unroll
            for (int i = 0; i < 4; i++)
                #pragma unroll
                for (int j = 0; j < 4; j++)
                    acc[i][j] = __builtin_amdgcn_mfma_f32_16x16x32_bf16(af[kk][i], bfr[kk][j], acc[i][j], 0, 0, 0);
    }

    if (EPI == 10 || EPI == 13){
        #pragma unroll
        for (int i = 0; i < 4; i++){
            float s = sqacc[i];
            s += __shfl_xor(s, 16);
            s += __shfl_xor(s, 32);
            if (l < 16) xds[wr * 64 + i * 16 + l] = (EPI == 10 ? 0.5f * s : s);
        }
    }
    __syncthreads();

    float* Cf = (float*)Cv + (long)b * sC;
    u16*   Cb = (u16*)Cv   + (EPI == 10 ? 0L : (EPI == 8 ? (long)bz : (long)b) * sC);

    if (EPI == 10 && bz == 0){
        #pragma unroll
        for (int i = 0; i < 4; i++){
            #pragma unroll
            for (int j = 0; j < 4; j++){
                const int col = col0 + wc * 64 + j * 16 + mr;
                if (CGUARD && col >= Ncols) continue;
                const int lrow = wr * 64 + i * 16 + g * 4;
                u16 pk[4];
                #pragma unroll
                for (int r = 0; r < 4; r++)
                    pk[r] = f2b(expf(acc[i][j][r] - xds[lrow + r]) * scale);
                *(ushort4*)&Cb[(long)col * ldc + row0 + lrow] = *(ushort4*)pk;
            }
        }
        return;
    }

    if (EPI == 9){
        #pragma unroll
        for (int i = 0; i < 4; i++){
            #pragma unroll
            for (int j = 0; j < 4; j++){
                const int col = col0 + wc * 64 + j * 16 + mr;
                if (CGUARD && col >= Ncols) continue;
                const float bv = bias[col];
                #pragma unroll
                for (int r = 0; r < 4; r++){
                    const int row = row0 + wr * 64 + i * 16 + g * 4 + r;
                    if (GUARD && row >= Mrows) continue;
                    const float vv = acc[i][j][r] + bv
                        + b2f(((const u16*)resid)[(long)row * ldr + col]);
                    Cf[(long)row * ldc + col] = vv;
                }
            }
        }
        return;
    }

    // ---- bf16 bounce epilogue (EPI 0,1,3,8,10z1,11,12,13) ----
    #pragma unroll
    for (int i = 0; i < 4; i++){
        #pragma unroll
        for (int j = 0; j < 4; j++){
            const int cl = wc * 64 + j * 16 + mr;
            const float bv = (EPI == 0 || EPI == 1 || EPI == 11 || EPI == 12)
                           ? bias[col0 + cl] : 0.f;
            u16 pk[4];
            #pragma unroll
            for (int r = 0; r < 4; r++){
                const int rl = wr * 64 + i * 16 + g * 4 + r;
                float vv = acc[i][j][r];
                if      (EPI == 1)  vv = gelu_f(vv + bv);
                else if (EPI == 3)  vv = vv / (rv[row0 + rl] + 1e-8f);
                else if (EPI == 13) vv = vv / (xds[rl] + 1e-8f);
                else if (EPI == 10) vv = expf(vv - xds[rl]) * scale;
                else                vv += bv;   // EPI 0, 8(+0), 11, 12
                pk[r] = f2b(vv);
                SMEM[rl * 128 + cl] = pk[r];
            }
            if (EPI == 12 && col0 >= 768){
                const int lrow = wr * 64 + i * 16 + g * 4;
                u16* vt = (u16*)resid;
                *(ushort4*)&vt[(long)(col0 + cl - 768) * ldr + row0 + lrow] = *(ushort4*)pk;
            }
        }
    }
    __syncthreads();

    u16* dst; long ld;
    if (EPI == 10){ dst = (u16*)resid; ld = ldr; }
    else          { dst = Cb;          ld = ldc; }
    #pragma unroll
    for (int s = 0; s < 8; s++){
        const int oi = s * 256 + tid;
        const int rl = oi >> 4, c8 = (oi & 15) << 3;
        const int row = row0 + rl, col = col0 + c8;
        if (GUARD && row >= Mrows) continue;
        if (CGUARD && col >= Ncols) continue;
        uint4 pv = *(uint4*)&SMEM[rl * 128 + c8];
        if (EPI == 11){
            const u16* rp = (const u16*)resid + (long)row * ldr + col;
            uint4 rv4 = *(const uint4*)rp;
            u16* a = (u16*)&pv; const u16* c = (const u16*)&rv4;
            #pragma unroll
            for (int e = 0; e < 8; e++) a[e] = f2b(b2f(a[e]) + b2f(c[e]));
        }
        *(uint4*)&dst[(long)row * ld + col] = pv;
    }
}

// LayerNorm over D=384, bf16 in/out, vectorized uint4 (8 bf16/lane, lanes 0-47).
__global__ __launch_bounds__(256)
void ln8_kernel(const u16* __restrict__ x, u16* __restrict__ o,
                const float* __restrict__ g, const float* __restrict__ bta)
{
    const int lane = threadIdx.x & 63;
    const long r = (long)blockIdx.x * 4 + (threadIdx.x >> 6);
    float v[8];
    float s = 0.f, q = 0.f;
    if (lane < 48){
        uint4 v4 = *(const uint4*)&x[r * 384 + lane * 8];
        const u16* h = (const u16*)&v4;
        #pragma unroll
        for (int e = 0; e < 8; e++){
            v[e] = b2f(h[e]);
            s += v[e];
            q += v[e] * v[e];
        }
    }
    #pragma unroll
    for (int off = 32; off; off >>= 1){
        s += __shfl_xor(s, off);
        q += __shfl_xor(q, off);
    }
    const float mu  = s * (1.0f / 384.0f);
    const float var = q * (1.0f / 384.0f) - mu * mu;
    const float inv = rsqrtf(var + 1e-5f);
    if (lane < 48){
        const int c0 = lane * 8;
        u16 pk[8];
        #pragma unroll
        for (int e = 0; e < 8; e++)
            pk[e] = f2b((v[e] - mu) * inv * g[c0 + e] + bta[c0 + e]);
        *(uint4*)&o[r * 384 + c0] = *(uint4*)pk;
    }
}

// kpsum[bl][m] = sum_t kpT[m][bl*T + t]
__global__ __launch_bounds__(256)
void kpsum2_kernel(const u16* __restrict__ kpT, float* __restrict__ kpsum, long Mc, int T)
{
    const int lane = threadIdx.x & 63;
    const int gw = blockIdx.x * 4 + (threadIdx.x >> 6);
    const int m = gw % 192, bl = gw / 192;
    const u16* row = kpT + (long)m * Mc + (long)bl * T;
    float s = 0.f;
    for (int i = lane; i < T; i += 64) s += b2f(row[i]);
    #pragma unroll
    for (int off = 32; off; off >>= 1) s += __shfl_xor(s, off);
    if (lane == 0) kpsum[bl * 192 + m] = s;
}

// concat(in1,in2) -> bf16 [Mc][768]; one 8-elem chunk per thread (direct)
__global__ __launch_bounds__(256)
void ca_kernel(const float* __restrict__ i1, const float* __restrict__ i2,
               u16* __restrict__ a0, long n8)
{
    const long idx = (long)blockIdx.x * 256 + threadIdx.x;
    if (idx >= n8) return;
    const long r = idx / 96;
    const int  c0 = (int)(idx % 96) * 8;
    const float* src = (c0 < 384) ? &i1[r * 384 + c0] : &i2[r * 384 + (c0 - 384)];
    float4 a = *(const float4*)src;
    float4 b = *(const float4*)(src + 4);
    uint4 pk;
    pk.x = (u32)f2b(a.x) | ((u32)f2b(a.y) << 16);
    pk.y = (u32)f2b(a.z) | ((u32)f2b(a.w) << 16);
    pk.z = (u32)f2b(b.x) | ((u32)f2b(b.y) << 16);
    pk.w = (u32)f2b(b.z) | ((u32)f2b(b.w) << 16);
    *(uint4*)&a0[r * 768 + c0] = pk;
}

// Fused weight prep (one dispatch; segments by flat element index)
__global__ __launch_bounds__(256)
void prep_kernel(const float* __restrict__ W1, const float* __restrict__ W2,
                 const float* __restrict__ kqv_w, const float* __restrict__ proj_w,
                 const float* __restrict__ mlp_w1, const float* __restrict__ mlp_w2,
                 const float* __restrict__ w_prm,
                 u16* __restrict__ w1t, u16* __restrict__ w2t, u16* __restrict__ kqvt,
                 u16* __restrict__ prjt, u16* __restrict__ m1t, u16* __restrict__ m2t,
                 u16* __restrict__ wprmb)
{
    const long i = (long)blockIdx.x * 256 + threadIdx.x;
    if (i < 294912){
        const long n = i / 768, k = i - n * 768;
        w1t[i] = f2b(W1[k * 384 + n]);
    } else if (i < 442368){
        const long j = i - 294912, n = j / 384, k = j - n * 384;
        w2t[j] = f2b(W2[k * 384 + n]);
    } else if (i < 884736){
        const long j = i - 442368, n = j / 384, k = j - n * 384;
        kqvt[j] = f2b(kqv_w[k * 1152 + n]);
    } else if (i < 1032192){
        const long j = i - 884736, n = j / 384, k = j - n * 384;
        prjt[j] = f2b(proj_w[k * 384 + n]);
    } else if (i < 1179648){
        const long j = i - 1032192, n = j / 384, k = j - n * 384;
        m1t[j] = f2b(mlp_w1[k * 384 + n]);
    } else if (i < 1327104){
        const long j = i - 1179648, n = j / 384, k = j - n * 384;
        m2t[j] = f2b(mlp_w2[k * 384 + n]);
    } else if (i < 1425408){
        const long j = i - 1327104;
        wprmb[j] = (j < 73728) ? f2b(w_prm[j]) : (u16)0;
    }
}

extern "C" void kernel_launch(void* const* d_in, const int* in_sizes, int n_in,
                              void* d_out, int out_size, void* d_ws, size_t ws_size,
                              hipStream_t stream)
{
    const long T = 3136;
    const float prm_scale = 0.07216878364870322f;  // 1/sqrt(192)

    const float* in1    = (const float*)d_in[0];
    const float* in2    = (const float*)d_in[1];
    const float* W1     = (const float*)d_in[2];
    const float* b1     = (const float*)d_in[3];
    const float* W2     = (const float*)d_in[4];
    const float* b2     = (const float*)d_in[5];
    const float* kqv_w  = (const float*)d_in[6];
    const float* kqv_b  = (const float*)d_in[7];
    const float* proj_w = (const float*)d_in[8];
    const float* proj_b = (const float*)d_in[9];
    const float* ln1_g  = (const float*)d_in[10];
    const float* ln1_b  = (const float*)d_in[11];
    const float* ln2_g  = (const float*)d_in[12];
    const float* ln2_b  = (const float*)d_in[13];
    const float* mlp_w1 = (const float*)d_in[14];
    const float* mlp_b1 = (const float*)d_in[15];
    const float* mlp_w2 = (const float*)d_in[16];
    const float* mlp_b2 = (const float*)d_in[17];
    const float* w_prm  = (const float*)d_in[18];
    float* out = (float*)d_out;

    char* p = (char*)d_ws;
    auto alloc = [&](long bytes)->char*{ char* r = p; p += (bytes + 255) & ~255L; return r; };

    // chunk-invariant bf16 weights
    u16* w1t   = (u16*)alloc(294912L * 2);
    u16* w2t   = (u16*)alloc(147456L * 2);
    u16* kqvt  = (u16*)alloc(442368L * 2);
    u16* prjt  = (u16*)alloc(147456L * 2);
    u16* m1t   = (u16*)alloc(147456L * 2);
    u16* m2t   = (u16*)alloc(147456L * 2);
    u16* wprmb = (u16*)alloc(256L * 384 * 2);
    char* chunkBase = p;

    const long perBatch = 2368L * T * 2
                        + 192L * 4 + 73728L * 2;
    const long fixed = (long)(chunkBase - (char*)d_ws) + (1L << 20);
    int nb = 2;
    for (int cand = 16; cand >= 2; cand >>= 1){
        if (fixed + (long)cand * perBatch + 128L * 1024 <= (long)ws_size){ nb = cand; break; }
    }

    const dim3 blk(256);

    prep_kernel<<<dim3((1425408 + 255) / 256), blk, 0, stream>>>(
        W1, W2, kqv_w, proj_w, mlp_w1, mlp_w2, w_prm,
        w1t, w2t, kqvt, prjt, m1t, m2t, wprmb);

    for (int b0 = 0; b0 < 16; b0 += nb){
        const long Mc = (long)nb * T;
        const int  gy128 = (int)(Mc / 128);
        const float* i1 = in1 + (long)b0 * T * 384;
        const float* i2 = in2 + (long)b0 * T * 384;
        float* outc = out + (long)b0 * T * 384;

        p = chunkBase;
        u16*  big   = (u16*)alloc(Mc * 1152 * 2);   // a0(768)+h1(tail) -> kqvb -> mlp hidden
        u16*  xb    = (u16*)alloc(Mc * 384 * 2);    // x -> xn -> t_att -> z
        u16*  qpb   = (u16*)alloc(Mc * 192 * 2);    // qp (followed by allocs: OOB pad)
        u16*  vT    = (u16*)alloc(384L * Mc * 2);   // v^T ; later y bf16
        u16*  kpT   = (u16*)alloc(256L * Mc * 2);   // kp^T (padded rows)
        float* kpsum= (float*)alloc((long)nb * 192 * 4);
        u16*  kptvb = (u16*)alloc((long)nb * 73728 * 2);
        (void)alloc(128L * 1024);

        u16* a0   = big;                      // [Mc][768]
        u16* h1   = big + Mc * 768;           // [Mc][384] (tail of big)
        u16* kqvb = big;                      // [Mc][1152] after a0/h1 dead
        u16* hbuf = big;                      // [Mc][384] after kqvb dead
        u16* ybf  = vT;                       // [Mc][384] after vT dead (post-kptv)

        // 0) a0 = bf16(concat), direct
        ca_kernel<<<dim3((unsigned)((Mc * 96 + 255) / 256)), blk, 0, stream>>>(
            i1, i2, a0, Mc * 96);
        // 1) h1 = GELU(a0 @ W1t^T + b1) -> big tail
        gemm_bf16<1,0,0,4><<<dim3(3, gy128, 1), blk, 0, stream>>>(
            a0, 768, w1t, 768, h1, 384, b1, nullptr, nullptr, 0,
            (int)Mc, 384, 768, 1, 0,0,0,0, 0.f);
        // 2) x = h1 @ W2t^T + b2 -> xb [bf16]
        gemm_bf16<0,0,0,4><<<dim3(3, gy128, 1), blk, 0, stream>>>(
            h1, 384, w2t, 384, xb, 384, b2, nullptr, nullptr, 0,
            (int)Mc, 384, 384, 1, 0,0,0,0, 0.f);
        // 3) LN1 in-place: xn -> xb
        ln8_kernel<<<dim3((unsigned)(Mc / 4)), blk, 0, stream>>>(xb, xb, ln1_g, ln1_b);
        // 4) kqv = xn @ kqvt^T + kqv_b -> big [N=1152] ; v col-tiles also -> vT
        gemm_bf16<12,0,0,4><<<dim3(9, gy128, 1), blk, 0, stream>>>(
            xb, 384, kqvt, 384, kqvb, 1152, kqv_b, nullptr, vT, (int)Mc,
            (int)Mc, 1152, 384, 1, 0,0,0,0, 0.f);
        // 5) FAVOR dual: z=0 kpT (transposed), z=1 qp (row); xd in-GEMM
        gemm_bf16<10,0,1,3><<<dim3(2, gy128, 2), blk, 0, stream>>>(
            kqvb, 1152, wprmb, 384, kpT, (int)Mc, nullptr, nullptr, qpb, 192,
            (int)Mc, 192, 384, 1, 384, 0, 0, 0, prm_scale);
        // 6) kpsum from kpT rows
        kpsum2_kernel<<<dim3(nb * 48), blk, 0, stream>>>(kpT, kpsum, Mc, (int)T);
        // 7) kptv direct: [384][192] = vT(b) @ kpT(b)^T, K=3136, bf16 out -> kptvb
        gemm_bf16<8,0,1,4><<<dim3(2, 3, nb), blk, 0, stream>>>(
            vT, (int)Mc, kpT, (int)Mc, kptvb, 192, nullptr, nullptr, nullptr, 0,
            384, 192, 3136, 1, 3136, 3136, 73728, 0, 0.f);
        // 8) t_att = (qp @ kptv^T)/(Dn+1e-8) -> xb  [Dn computed in-GEMM from kpsum]
        gemm_bf16<13,1,0,4><<<dim3(3, 25, nb), blk, 0, stream>>>(
            qpb, 192, kptvb, 192, xb, 384, nullptr, kpsum, nullptr, 0,
            (int)T, 384, 192, 1, T*192, 73728, T*384, 192, 0.f);
        // 9) y = t_att @ proj + proj_b + v(bf16) -> ybf [bf16] (vT dead)
        gemm_bf16<11,0,0,4><<<dim3(3, gy128, 1), blk, 0, stream>>>(
            xb, 384, prjt, 384, ybf, 384, proj_b, nullptr, kqvb + 768, 1152,
            (int)Mc, 384, 384, 1, 0,0,0,0, 0.f);
        // 10) LN2: z -> xb
        ln8_kernel<<<dim3((unsigned)(Mc / 4)), blk, 0, stream>>>(ybf, xb, ln2_g, ln2_b);
        // 11) h = GELU(z @ mlp1 + b) -> hbuf
        gemm_bf16<1,0,0,4><<<dim3(3, gy128, 1), blk, 0, stream>>>(
            xb, 384, m1t, 384, hbuf, 384, mlp_b1, nullptr, nullptr, 0,
            (int)Mc, 384, 384, 1, 0,0,0,0, 0.f);
        // 12) out = h @ mlp2 + b + y(bf16)  [f32 direct scatter]
        gemm_bf16<9,0,0,4><<<dim3(3, gy128, 1), blk, 0, stream>>>(
            hbuf, 384, m2t, 384, outc, 384, mlp_b2, nullptr, ybf, 384,
            (int)Mc, 384, 384, 1, 0,0,0,0, 0.f);
    }
}

// Round 21
// 500.738 us; speedup vs baseline: 1.0523x; 1.0523x over previous
//
#include <hip/hip_runtime.h>
#include <math.h>

typedef unsigned short u16;
typedef unsigned int   u32;
typedef __attribute__((ext_vector_type(8))) short short8;
typedef __attribute__((ext_vector_type(4))) float f32x4;

typedef const void __attribute__((address_space(1))) gvoid_t;
typedef void       __attribute__((address_space(3))) svoid_t;

__device__ __forceinline__ void gload_lds16(const void* g, void* l){
    __builtin_amdgcn_global_load_lds((gvoid_t*)g, (svoid_t*)l, 16, 0, 0);
}

__device__ __forceinline__ float gelu_f(float x){
    return 0.5f * x * (1.0f + erff(x * 0.70710678118654752f));
}
__device__ __forceinline__ u16 f2b(float x){
    union{float f; u32 u;} v; v.f = x;
    u32 r = (v.u + 0x7fffu + ((v.u >> 16) & 1u)) >> 16;
    return (u16)r;
}
__device__ __forceinline__ float b2f(u16 h){
    union{u32 u; float f;} v; v.u = ((u32)h) << 16; return v.f;
}

// ===================== bf16 MFMA GEMM (frozen; EPI13 reverted) =====================
// Tile 128x128, BK=64, 4 waves, XOR-swizzled LDS, global_load_lds staging,
// T1 XCD-chunked block swizzle. MINW = min waves/EU occupancy hint.
// EPI: 0:+bias->bf16  1:+bias,GELU->bf16  3:/(rowv[r]+1e-8)->bf16
//      8:plain bf16 store (per-splitK slice bz*sC; splitK=1 -> per-batch)
//      9:+bias+resid(bf16,ldr)->f32 DIRECT scatter
//      10:FAVOR dual (in-GEMM xd): z0 transposed kpT store; z1 qp row store->resid
//      11:+bias+resid(bf16,ldr)->bf16
//      12:+bias->bf16 row store; col-tiles >=768 ALSO transposed into resid[ldr] (vT)
template<int EPI, int GUARD, int CGUARD, int MINW>
__global__ __launch_bounds__(256, MINW)
void gemm_bf16(const u16* __restrict__ A, int lda,
               const u16* __restrict__ B, int ldb,
               void* __restrict__ Cv, int ldc,
               const float* __restrict__ bias,
               const float* __restrict__ rowv,
               void* __restrict__ resid, int ldr,
               int Mrows, int Ncols, int K, int splitK,
               long sA, long sB, long sC, long sRV,
               float scale)
{
    const int bz = blockIdx.z;
    const int b  = bz / splitK, kc = bz % splitK;
    A += (long)b * sA;  B += (long)b * sB;
    const float* rv = (EPI == 3) ? rowv + (long)b * sRV : nullptr;

    __shared__ u16 SMEM[16384];     // 32KB
    __shared__ float xds[128];
    u16* const As = SMEM;
    u16* const Bs = SMEM + 8192;

    const int tid = threadIdx.x;

    const int gx  = gridDim.x;
    const int nwg = gx * gridDim.y;
    const int L   = blockIdx.y * gx + blockIdx.x;
    const int q8  = nwg >> 3, r8 = nwg & 7;
    const int xc  = L & 7,   i8 = L >> 3;
    const int nid = (xc < r8 ? xc * (q8 + 1) : r8 * (q8 + 1) + (xc - r8) * q8) + i8;
    const int row0 = (nid / gx) * 128, col0 = (nid % gx) * 128;

    f32x4 acc[4][4] = {};
    float sqacc[4] = {0.f, 0.f, 0.f, 0.f};

    const int l  = tid & 63, w4 = tid >> 6;
    const int wr = w4 >> 1, wc = w4 & 1;
    const int g  = l >> 4,  mr = l & 15;

    const int kLen   = K / splitK;
    const int kStart = kc * kLen;
    const int nt     = kLen / 64;

    const int m0   = w4 * 8 + (l >> 3);
    const int k8s  = (l & 7) ^ (m0 & 7);
    const int lBase = w4 * 512 + l * 8;
    const u16* gA0 = A + (long)(row0 + m0) * lda + kStart + k8s * 8;
    const u16* gB0 = B + (long)(col0 + m0) * ldb + kStart + k8s * 8;

    int aOff[4], bOff[4], sl[2];
    #pragma unroll
    for (int i = 0; i < 4; i++){
        aOff[i] = (wr * 64 + i * 16 + mr) * 64;
        bOff[i] = (wc * 64 + i * 16 + mr) * 64;
    }
    #pragma unroll
    for (int kk = 0; kk < 2; kk++)
        sl[kk] = (((kk * 4 + g) ^ (mr & 7)) & 7) * 8;

    for (int t = 0; t < nt; t++){
        __syncthreads();
        #pragma unroll
        for (int q = 0; q < 4; q++){
            gload_lds16(gA0 + (long)q * 32 * lda + t * 64, &As[lBase + q * 2048]);
            gload_lds16(gB0 + (long)q * 32 * ldb + t * 64, &Bs[lBase + q * 2048]);
        }
        __syncthreads();

        short8 af[2][4], bfr[2][4];
        #pragma unroll
        for (int kk = 0; kk < 2; kk++)
            #pragma unroll
            for (int i = 0; i < 4; i++){
                af[kk][i]  = *(const short8*)&As[aOff[i] + sl[kk]];
                bfr[kk][i] = *(const short8*)&Bs[bOff[i] + sl[kk]];
            }
        if (EPI == 10){
            #pragma unroll
            for (int kk = 0; kk < 2; kk++)
                #pragma unroll
                for (int i = 0; i < 4; i++)
                    #pragma unroll
                    for (int e = 0; e < 8; e++){
                        float f_ = b2f((u16)af[kk][i][e]);
                        sqacc[i] += f_ * f_;
                    }
        }
        #pragma unroll
        for (int kk = 0; kk < 2; kk++)
            #pragma unroll
            for (int i = 0; i < 4; i++)
                #pragma unroll
                for (int j = 0; j < 4; j++)
                    acc[i][j] = __builtin_amdgcn_mfma_f32_16x16x32_bf16(af[kk][i], bfr[kk][j], acc[i][j], 0, 0, 0);
    }

    if (EPI == 10){
        #pragma unroll
        for (int i = 0; i < 4; i++){
            float s = sqacc[i];
            s += __shfl_xor(s, 16);
            s += __shfl_xor(s, 32);
            if (l < 16) xds[wr * 64 + i * 16 + l] = 0.5f * s;
        }
    }
    __syncthreads();

    float* Cf = (float*)Cv + (long)b * sC;
    u16*   Cb = (u16*)Cv   + (EPI == 10 ? 0L : (EPI == 8 ? (long)bz : (long)b) * sC);

    if (EPI == 10 && bz == 0){
        #pragma unroll
        for (int i = 0; i < 4; i++){
            #pragma unroll
            for (int j = 0; j < 4; j++){
                const int col = col0 + wc * 64 + j * 16 + mr;
                if (CGUARD && col >= Ncols) continue;
                const int lrow = wr * 64 + i * 16 + g * 4;
                u16 pk[4];
                #pragma unroll
                for (int r = 0; r < 4; r++)
                    pk[r] = f2b(expf(acc[i][j][r] - xds[lrow + r]) * scale);
                *(ushort4*)&Cb[(long)col * ldc + row0 + lrow] = *(ushort4*)pk;
            }
        }
        return;
    }

    if (EPI == 9){
        #pragma unroll
        for (int i = 0; i < 4; i++){
            #pragma unroll
            for (int j = 0; j < 4; j++){
                const int col = col0 + wc * 64 + j * 16 + mr;
                if (CGUARD && col >= Ncols) continue;
                const float bv = bias[col];
                #pragma unroll
                for (int r = 0; r < 4; r++){
                    const int row = row0 + wr * 64 + i * 16 + g * 4 + r;
                    if (GUARD && row >= Mrows) continue;
                    const float vv = acc[i][j][r] + bv
                        + b2f(((const u16*)resid)[(long)row * ldr + col]);
                    Cf[(long)row * ldc + col] = vv;
                }
            }
        }
        return;
    }

    // ---- bf16 bounce epilogue (EPI 0,1,3,8,10z1,11,12) ----
    #pragma unroll
    for (int i = 0; i < 4; i++){
        #pragma unroll
        for (int j = 0; j < 4; j++){
            const int cl = wc * 64 + j * 16 + mr;
            const float bv = (EPI == 0 || EPI == 1 || EPI == 11 || EPI == 12)
                           ? bias[col0 + cl] : 0.f;
            u16 pk[4];
            #pragma unroll
            for (int r = 0; r < 4; r++){
                const int rl = wr * 64 + i * 16 + g * 4 + r;
                float vv = acc[i][j][r];
                if      (EPI == 1)  vv = gelu_f(vv + bv);
                else if (EPI == 3)  vv = vv / (rv[row0 + rl] + 1e-8f);
                else if (EPI == 10) vv = expf(vv - xds[rl]) * scale;
                else                vv += bv;   // EPI 0, 8(+0), 11, 12
                pk[r] = f2b(vv);
                SMEM[rl * 128 + cl] = pk[r];
            }
            if (EPI == 12 && col0 >= 768){
                const int lrow = wr * 64 + i * 16 + g * 4;
                u16* vt = (u16*)resid;
                *(ushort4*)&vt[(long)(col0 + cl - 768) * ldr + row0 + lrow] = *(ushort4*)pk;
            }
        }
    }
    __syncthreads();

    u16* dst; long ld;
    if (EPI == 10){ dst = (u16*)resid; ld = ldr; }
    else          { dst = Cb;          ld = ldc; }
    #pragma unroll
    for (int s = 0; s < 8; s++){
        const int oi = s * 256 + tid;
        const int rl = oi >> 4, c8 = (oi & 15) << 3;
        const int row = row0 + rl, col = col0 + c8;
        if (GUARD && row >= Mrows) continue;
        if (CGUARD && col >= Ncols) continue;
        uint4 pv = *(uint4*)&SMEM[rl * 128 + c8];
        if (EPI == 11){
            const u16* rp = (const u16*)resid + (long)row * ldr + col;
            uint4 rv4 = *(const uint4*)rp;
            u16* a = (u16*)&pv; const u16* c = (const u16*)&rv4;
            #pragma unroll
            for (int e = 0; e < 8; e++) a[e] = f2b(b2f(a[e]) + b2f(c[e]));
        }
        *(uint4*)&dst[(long)row * ld + col] = pv;
    }
}

// LayerNorm over D=384, bf16 in/out, vectorized uint4 (8 bf16/lane, lanes 0-47).
__global__ __launch_bounds__(256)
void ln8_kernel(const u16* __restrict__ x, u16* __restrict__ o,
                const float* __restrict__ g, const float* __restrict__ bta)
{
    const int lane = threadIdx.x & 63;
    const long r = (long)blockIdx.x * 4 + (threadIdx.x >> 6);
    float v[8];
    float s = 0.f, q = 0.f;
    if (lane < 48){
        uint4 v4 = *(const uint4*)&x[r * 384 + lane * 8];
        const u16* h = (const u16*)&v4;
        #pragma unroll
        for (int e = 0; e < 8; e++){
            v[e] = b2f(h[e]);
            s += v[e];
            q += v[e] * v[e];
        }
    }
    #pragma unroll
    for (int off = 32; off; off >>= 1){
        s += __shfl_xor(s, off);
        q += __shfl_xor(q, off);
    }
    const float mu  = s * (1.0f / 384.0f);
    const float var = q * (1.0f / 384.0f) - mu * mu;
    const float inv = rsqrtf(var + 1e-5f);
    if (lane < 48){
        const int c0 = lane * 8;
        u16 pk[8];
        #pragma unroll
        for (int e = 0; e < 8; e++)
            pk[e] = f2b((v[e] - mu) * inv * g[c0 + e] + bta[c0 + e]);
        *(uint4*)&o[r * 384 + c0] = *(uint4*)pk;
    }
}

// Dn[r] = dot(qp_bf16[r,:192], kpsum[r/T,:192])
__global__ __launch_bounds__(256)
void dn_kernel(const u16* __restrict__ qp, const float* __restrict__ kpsum,
               float* __restrict__ Dn, int T)
{
    const int lane = threadIdx.x & 63;
    const long r = (long)blockIdx.x * 4 + (threadIdx.x >> 6);
    const int b = (int)(r / T);
    const u16* qr = qp + r * 192;
    const float* ks = kpsum + (long)b * 192;
    float s = 0.f;
    #pragma unroll
    for (int i = 0; i < 3; i++){ const int m = lane + i*64; s += b2f(qr[m]) * ks[m]; }
    #pragma unroll
    for (int off = 32; off; off >>= 1) s += __shfl_xor(s, off);
    if (lane == 0) Dn[r] = s;
}

// kpsum[bl][m] = sum_t kpT[m][bl*T + t]
__global__ __launch_bounds__(256)
void kpsum2_kernel(const u16* __restrict__ kpT, float* __restrict__ kpsum, long Mc, int T)
{
    const int lane = threadIdx.x & 63;
    const int gw = blockIdx.x * 4 + (threadIdx.x >> 6);
    const int m = gw % 192, bl = gw / 192;
    const u16* row = kpT + (long)m * Mc + (long)bl * T;
    float s = 0.f;
    for (int i = lane; i < T; i += 64) s += b2f(row[i]);
    #pragma unroll
    for (int off = 32; off; off >>= 1) s += __shfl_xor(s, off);
    if (lane == 0) kpsum[bl * 192 + m] = s;
}

// concat(in1,in2) -> bf16 [Mc][768]; one 8-elem chunk per thread (direct)
__global__ __launch_bounds__(256)
void ca_kernel(const float* __restrict__ i1, const float* __restrict__ i2,
               u16* __restrict__ a0, long n8)
{
    const long idx = (long)blockIdx.x * 256 + threadIdx.x;
    if (idx >= n8) return;
    const long r = idx / 96;
    const int  c0 = (int)(idx % 96) * 8;
    const float* src = (c0 < 384) ? &i1[r * 384 + c0] : &i2[r * 384 + (c0 - 384)];
    float4 a = *(const float4*)src;
    float4 b = *(const float4*)(src + 4);
    uint4 pk;
    pk.x = (u32)f2b(a.x) | ((u32)f2b(a.y) << 16);
    pk.y = (u32)f2b(a.z) | ((u32)f2b(a.w) << 16);
    pk.z = (u32)f2b(b.x) | ((u32)f2b(b.y) << 16);
    pk.w = (u32)f2b(b.z) | ((u32)f2b(b.w) << 16);
    *(uint4*)&a0[r * 768 + c0] = pk;
}

// Fused weight prep (one dispatch; segments by flat element index)
__global__ __launch_bounds__(256)
void prep_kernel(const float* __restrict__ W1, const float* __restrict__ W2,
                 const float* __restrict__ kqv_w, const float* __restrict__ proj_w,
                 const float* __restrict__ mlp_w1, const float* __restrict__ mlp_w2,
                 const float* __restrict__ w_prm,
                 u16* __restrict__ w1t, u16* __restrict__ w2t, u16* __restrict__ kqvt,
                 u16* __restrict__ prjt, u16* __restrict__ m1t, u16* __restrict__ m2t,
                 u16* __restrict__ wprmb)
{
    const long i = (long)blockIdx.x * 256 + threadIdx.x;
    if (i < 294912){
        const long n = i / 768, k = i - n * 768;
        w1t[i] = f2b(W1[k * 384 + n]);
    } else if (i < 442368){
        const long j = i - 294912, n = j / 384, k = j - n * 384;
        w2t[j] = f2b(W2[k * 384 + n]);
    } else if (i < 884736){
        const long j = i - 442368, n = j / 384, k = j - n * 384;
        kqvt[j] = f2b(kqv_w[k * 1152 + n]);
    } else if (i < 1032192){
        const long j = i - 884736, n = j / 384, k = j - n * 384;
        prjt[j] = f2b(proj_w[k * 384 + n]);
    } else if (i < 1179648){
        const long j = i - 1032192, n = j / 384, k = j - n * 384;
        m1t[j] = f2b(mlp_w1[k * 384 + n]);
    } else if (i < 1327104){
        const long j = i - 1179648, n = j / 384, k = j - n * 384;
        m2t[j] = f2b(mlp_w2[k * 384 + n]);
    } else if (i < 1425408){
        const long j = i - 1327104;
        wprmb[j] = (j < 73728) ? f2b(w_prm[j]) : (u16)0;
    }
}

extern "C" void kernel_launch(void* const* d_in, const int* in_sizes, int n_in,
                              void* d_out, int out_size, void* d_ws, size_t ws_size,
                              hipStream_t stream)
{
    const long T = 3136;
    const float prm_scale = 0.07216878364870322f;  // 1/sqrt(192)

    const float* in1    = (const float*)d_in[0];
    const float* in2    = (const float*)d_in[1];
    const float* W1     = (const float*)d_in[2];
    const float* b1     = (const float*)d_in[3];
    const float* W2     = (const float*)d_in[4];
    const float* b2     = (const float*)d_in[5];
    const float* kqv_w  = (const float*)d_in[6];
    const float* kqv_b  = (const float*)d_in[7];
    const float* proj_w = (const float*)d_in[8];
    const float* proj_b = (const float*)d_in[9];
    const float* ln1_g  = (const float*)d_in[10];
    const float* ln1_b  = (const float*)d_in[11];
    const float* ln2_g  = (const float*)d_in[12];
    const float* ln2_b  = (const float*)d_in[13];
    const float* mlp_w1 = (const float*)d_in[14];
    const float* mlp_b1 = (const float*)d_in[15];
    const float* mlp_w2 = (const float*)d_in[16];
    const float* mlp_b2 = (const float*)d_in[17];
    const float* w_prm  = (const float*)d_in[18];
    float* out = (float*)d_out;

    char* p = (char*)d_ws;
    auto alloc = [&](long bytes)->char*{ char* r = p; p += (bytes + 255) & ~255L; return r; };

    // chunk-invariant bf16 weights
    u16* w1t   = (u16*)alloc(294912L * 2);
    u16* w2t   = (u16*)alloc(147456L * 2);
    u16* kqvt  = (u16*)alloc(442368L * 2);
    u16* prjt  = (u16*)alloc(147456L * 2);
    u16* m1t   = (u16*)alloc(147456L * 2);
    u16* m2t   = (u16*)alloc(147456L * 2);
    u16* wprmb = (u16*)alloc(256L * 384 * 2);
    char* chunkBase = p;

    const long perBatch = 2368L * T * 2 + T * 4
                        + 192L * 4 + 73728L * 2;
    const long fixed = (long)(chunkBase - (char*)d_ws) + (1L << 20);
    int nb = 2;
    for (int cand = 16; cand >= 2; cand >>= 1){
        if (fixed + (long)cand * perBatch + 128L * 1024 <= (long)ws_size){ nb = cand; break; }
    }

    const dim3 blk(256);

    prep_kernel<<<dim3((1425408 + 255) / 256), blk, 0, stream>>>(
        W1, W2, kqv_w, proj_w, mlp_w1, mlp_w2, w_prm,
        w1t, w2t, kqvt, prjt, m1t, m2t, wprmb);

    for (int b0 = 0; b0 < 16; b0 += nb){
        const long Mc = (long)nb * T;
        const int  gy128 = (int)(Mc / 128);
        const float* i1 = in1 + (long)b0 * T * 384;
        const float* i2 = in2 + (long)b0 * T * 384;
        float* outc = out + (long)b0 * T * 384;

        p = chunkBase;
        u16*  big   = (u16*)alloc(Mc * 1152 * 2);   // a0(768)+h1(tail) -> kqvb -> mlp hidden
        u16*  xb    = (u16*)alloc(Mc * 384 * 2);    // x -> xn -> t_att -> z
        u16*  qpb   = (u16*)alloc(Mc * 192 * 2);    // qp (followed by allocs: OOB pad)
        u16*  vT    = (u16*)alloc(384L * Mc * 2);   // v^T ; later y bf16
        u16*  kpT   = (u16*)alloc(256L * Mc * 2);   // kp^T (padded rows)
        float* Dn   = (float*)alloc(Mc * 4);
        float* kpsum= (float*)alloc((long)nb * 192 * 4);
        u16*  kptvb = (u16*)alloc((long)nb * 73728 * 2);
        (void)alloc(128L * 1024);

        u16* a0   = big;                      // [Mc][768]
        u16* h1   = big + Mc * 768;           // [Mc][384] (tail of big)
        u16* kqvb = big;                      // [Mc][1152] after a0/h1 dead
        u16* hbuf = big;                      // [Mc][384] after kqvb dead
        u16* ybf  = vT;                       // [Mc][384] after vT dead (post-kptv)

        // 0) a0 = bf16(concat), direct
        ca_kernel<<<dim3((unsigned)((Mc * 96 + 255) / 256)), blk, 0, stream>>>(
            i1, i2, a0, Mc * 96);
        // 1) h1 = GELU(a0 @ W1t^T + b1) -> big tail
        gemm_bf16<1,0,0,4><<<dim3(3, gy128, 1), blk, 0, stream>>>(
            a0, 768, w1t, 768, h1, 384, b1, nullptr, nullptr, 0,
            (int)Mc, 384, 768, 1, 0,0,0,0, 0.f);
        // 2) x = h1 @ W2t^T + b2 -> xb [bf16]
        gemm_bf16<0,0,0,4><<<dim3(3, gy128, 1), blk, 0, stream>>>(
            h1, 384, w2t, 384, xb, 384, b2, nullptr, nullptr, 0,
            (int)Mc, 384, 384, 1, 0,0,0,0, 0.f);
        // 3) LN1 in-place: xn -> xb
        ln8_kernel<<<dim3((unsigned)(Mc / 4)), blk, 0, stream>>>(xb, xb, ln1_g, ln1_b);
        // 4) kqv = xn @ kqvt^T + kqv_b -> big [N=1152] ; v col-tiles also -> vT
        gemm_bf16<12,0,0,4><<<dim3(9, gy128, 1), blk, 0, stream>>>(
            xb, 384, kqvt, 384, kqvb, 1152, kqv_b, nullptr, vT, (int)Mc,
            (int)Mc, 1152, 384, 1, 0,0,0,0, 0.f);
        // 5) FAVOR dual: z=0 kpT (transposed), z=1 qp (row); xd in-GEMM
        gemm_bf16<10,0,1,3><<<dim3(2, gy128, 2), blk, 0, stream>>>(
            kqvb, 1152, wprmb, 384, kpT, (int)Mc, nullptr, nullptr, qpb, 192,
            (int)Mc, 192, 384, 1, 384, 0, 0, 0, prm_scale);
        // 6) kpsum from kpT rows
        kpsum2_kernel<<<dim3(nb * 48), blk, 0, stream>>>(kpT, kpsum, Mc, (int)T);
        // 7) kptv direct: [384][192] = vT(b) @ kpT(b)^T, K=3136, bf16 out -> kptvb
        gemm_bf16<8,0,1,4><<<dim3(2, 3, nb), blk, 0, stream>>>(
            vT, (int)Mc, kpT, (int)Mc, kptvb, 192, nullptr, nullptr, nullptr, 0,
            384, 192, 3136, 1, 3136, 3136, 73728, 0, 0.f);
        // 8) Dn
        dn_kernel<<<dim3((unsigned)(Mc / 4)), blk, 0, stream>>>(qpb, kpsum, Dn, (int)T);
        // 9) t_att = (qp @ kptv^T)/(Dn+1e-8) -> xb
        gemm_bf16<3,1,0,4><<<dim3(3, 25, nb), blk, 0, stream>>>(
            qpb, 192, kptvb, 192, xb, 384, nullptr, Dn, nullptr, 0,
            (int)T, 384, 192, 1, T*192, 73728, T*384, T, 0.f);
        // 10) y = t_att @ proj + proj_b + v(bf16) -> ybf [bf16] (vT dead)
        gemm_bf16<11,0,0,4><<<dim3(3, gy128, 1), blk, 0, stream>>>(
            xb, 384, prjt, 384, ybf, 384, proj_b, nullptr, kqvb + 768, 1152,
            (int)Mc, 384, 384, 1, 0,0,0,0, 0.f);
        // 11) LN2: z -> xb
        ln8_kernel<<<dim3((unsigned)(Mc / 4)), blk, 0, stream>>>(ybf, xb, ln2_g, ln2_b);
        // 12) h = GELU(z @ mlp1 + b) -> hbuf
        gemm_bf16<1,0,0,4><<<dim3(3, gy128, 1), blk, 0, stream>>>(
            xb, 384, m1t, 384, hbuf, 384, mlp_b1, nullptr, nullptr, 0,
            (int)Mc, 384, 384, 1, 0,0,0,0, 0.f);
        // 13) out = h @ mlp2 + b + y(bf16)  [f32 direct scatter]
        gemm_bf16<9,0,0,4><<<dim3(3, gy128, 1), blk, 0, stream>>>(
            hbuf, 384, m2t, 384, outc, 384, mlp_b2, nullptr, ybf, 384,
            (int)Mc, 384, 384, 1, 0,0,0,0, 0.f);
    }
}